// Round 2
// baseline (1548.518 us; speedup 1.0000x reference)
//
#include <hip/hip_runtime.h>
#include <math.h>

// B=512, N=128, E=256, H=8, D=32. All fp32 (argmax fidelity requires it).
//
// Round-8: restructure k_roll 8-wave -> 16-wave (1024 thr), 2 waves per head.
//  R6/R7 proved the allocator will not budge from 128 VGPRs (two occupancy
//  attributes, zero codegen change), and 192 floats/thread of k/v/lk state
//  cannot fit -> 40MB scratch WRITE_SIZE + reload stalls = the 36% VALU-idle.
//  Fix: halve per-thread state to 96 floats (kr32+vr32+lr32) by splitting each
//  head across 2 waves (wave w=2h+u owns n-half u). Split softmax handled with
//  per-wave (m_u,S_u) + alpha-correction folded into the z phase (linearity),
//  so only TWO barriers/step. Phase-C LSE (tanh/exp/log) runs on wave 0 only;
//  argmax stays redundant on all waves so `action` needs no extra barrier.
//  Side benefit: 4 waves/SIMD (vs 2) for latency hiding; LDS unchanged.

#define B_ 512
#define N_ 128
#define E_ 256
#define H_ 8
#define D_ 32
#define NEG (-1.0e9f)
#define CLIPV 10.0f
#define SCALE 0.17677669529663688110f  /* 1/sqrt(32), fp32-rounded */

// ---------------- wave-wide reductions (64 lanes) ----------------
template <int CTRL>
__device__ __forceinline__ float dpp_f(float x) {
  int r = __builtin_amdgcn_update_dpp(__float_as_int(x), __float_as_int(x),
                                      CTRL, 0xf, 0xf, false);
  return __int_as_float(r);
}
__device__ __forceinline__ float wred_max(float v) {
  v = fmaxf(v, dpp_f<0xB1>(v));    // quad_perm(1,0,3,2)  : xor 1
  v = fmaxf(v, dpp_f<0x4E>(v));    // quad_perm(2,3,0,1)  : xor 2
  v = fmaxf(v, dpp_f<0x124>(v));   // row_ror:4
  v = fmaxf(v, dpp_f<0x128>(v));   // row_ror:8
  v = fmaxf(v, __shfl_xor(v, 16));
  v = fmaxf(v, __shfl_xor(v, 32));
  return v;
}
__device__ __forceinline__ float wred_sum(float v) {
  v += dpp_f<0xB1>(v);
  v += dpp_f<0x4E>(v);
  v += dpp_f<0x124>(v);
  v += dpp_f<0x128>(v);
  v += __shfl_xor(v, 16);
  v += __shfl_xor(v, 32);
  return v;
}

// ---------------------------------------------------------------- K0: weight folds
__global__ void k0_prep(const float* __restrict__ Wqkv, const float* __restrict__ bqkv,
                        const float* __restrict__ Wmlp, const float* __restrict__ bmlp,
                        float* __restrict__ Wc, float* __restrict__ bc,
                        float* __restrict__ wc2, float* __restrict__ cconst) {
  int t = threadIdx.x;
  int blk = blockIdx.x;
  __shared__ float row_s[E_];
  if (blk < E_) {
    int g = blk;
    row_s[t] = Wqkv[g * 768 + 512 + t];
    __syncthreads();
    int f = t;
    const float4* wm4 = (const float4*)(Wmlp + f * E_);
    const float4* w34 = (const float4*)row_s;
    float acc = 0.f;
#pragma unroll 8
    for (int j = 0; j < E_ / 4; ++j) {
      float4 a = w34[j]; float4 bv = wm4[j];
      acc += a.x * bv.x + a.y * bv.y + a.z * bv.z + a.w * bv.w;
    }
    Wc[g * E_ + f] = acc;
  } else {
    int f = t;
    float a1 = 0.f, a2 = 0.f;
    for (int e = 0; e < E_; ++e) {
      a1 += bqkv[512 + e] * Wmlp[f * E_ + e];
      a2 += Wqkv[f * 768 + 512 + e] * bmlp[e];
    }
    bc[f] = a1;
    wc2[f] = a2;
    if (t == 0) {
      float c = 0.f;
      for (int e = 0; e < E_; ++e) c += bqkv[512 + e] * bmlp[e];
      *cconst = c;
    }
  }
}

// ---------------------------------------------------------------- K1: precompute GEMM (3 tensors)
__global__ __launch_bounds__(256, 2)
void k_gemm(const float* __restrict__ emb, const float* __restrict__ Wqkv,
            const float* __restrict__ bqkv,
            const float* __restrict__ Wc, const float* __restrict__ bc,
            float* __restrict__ kk_, float* __restrict__ vv_,
            float* __restrict__ lk2, int ncc, int tmask) {
  __shared__ float As[256 * 64];  // [kk][m], exactly 64 KiB
  int t = threadIdx.x;
  int r0 = blockIdx.x * 64;
  {
    int m = t >> 2;
    int c0 = t & 3;
    const float4* e4 = (const float4*)emb;
#pragma unroll
    for (int p = 0; p < 16; ++p) {
      int c4 = c0 + p * 4;
      float4 a = e4[(size_t)(r0 + m) * 64 + c4];
      As[(c4 * 4 + 0) * 64 + m] = a.x;
      As[(c4 * 4 + 1) * 64 + m] = a.y;
      As[(c4 * 4 + 2) * 64 + m] = a.z;
      As[(c4 * 4 + 3) * 64 + m] = a.w;
    }
  }
  __syncthreads();
  int tx = t & 15, ty = t >> 4;
  const float4* As4 = (const float4*)As;
  for (int cc = 0; cc < ncc; ++cc) {
    const float* Bp; int ldb4; const float* bias; float* outp;
    int colbase = (cc & 1) * 128;
    switch (cc >> 1) {
      case 0:  Bp = Wqkv + colbase;          ldb4 = 192; bias = bqkv + colbase;       outp = kk_; break;
      case 1:  Bp = Wqkv + 256 + colbase;    ldb4 = 192; bias = bqkv + 256 + colbase; outp = vv_; break;
      default: Bp = Wc + colbase;            ldb4 = 64;  bias = bc + colbase;         outp = lk2; break;
    }
    const float4* B4 = (const float4*)Bp;
    float acc[4][8];
#pragma unroll
    for (int i = 0; i < 4; ++i)
#pragma unroll
      for (int j = 0; j < 8; ++j) acc[i][j] = 0.f;

#pragma unroll 4
    for (int kk = 0; kk < 256; ++kk) {
      float4 b0 = B4[kk * ldb4 + tx * 2];
      float4 b1 = B4[kk * ldb4 + tx * 2 + 1];
      float4 av = As4[kk * 16 + ty];
      float a_[4] = {av.x, av.y, av.z, av.w};
#pragma unroll
      for (int i = 0; i < 4; ++i) {
        acc[i][0] += a_[i] * b0.x; acc[i][1] += a_[i] * b0.y;
        acc[i][2] += a_[i] * b0.z; acc[i][3] += a_[i] * b0.w;
        acc[i][4] += a_[i] * b1.x; acc[i][5] += a_[i] * b1.y;
        acc[i][6] += a_[i] * b1.z; acc[i][7] += a_[i] * b1.w;
      }
    }
    float bj[8];
#pragma unroll
    for (int j = 0; j < 8; ++j) bj[j] = bias ? bias[tx * 8 + j] : 0.f;
    int tr = (tmask >> (cc >> 1)) & 1;
    if (!tr) {
#pragma unroll
      for (int i = 0; i < 4; ++i) {
        int row = r0 + ty * 4 + i;
        float4 o0 = make_float4(acc[i][0] + bj[0], acc[i][1] + bj[1], acc[i][2] + bj[2], acc[i][3] + bj[3]);
        float4 o1 = make_float4(acc[i][4] + bj[4], acc[i][5] + bj[5], acc[i][6] + bj[6], acc[i][7] + bj[7]);
        float4* o4 = (float4*)(outp + (size_t)row * 256 + colbase + tx * 8);
        o4[0] = o0; o4[1] = o1;
      }
    } else {
#pragma unroll
      for (int i = 0; i < 4; ++i) {
        int row = r0 + ty * 4 + i;
        int bb = row >> 7, nn = row & 127;
        float* op = outp + (size_t)bb * 32768 + nn;
#pragma unroll
        for (int j = 0; j < 8; ++j)
          op[(size_t)(colbase + tx * 8 + j) * 128] = acc[i][j] + bj[j];
      }
    }
  }
}

// ---------------------------------------------------------------- K2: qbase per b
__global__ void k_qbase(const float* __restrict__ emb, const float* __restrict__ Wfix,
                        const float* __restrict__ bfix, const float* __restrict__ Wstep,
                        const float* __restrict__ bstep, float* __restrict__ qbase) {
  int b = blockIdx.x, t = threadIdx.x;
  __shared__ float ge[E_], fi[E_];
  const float* eb = emb + (size_t)b * N_ * E_;
  float s = 0.f;
#pragma unroll 8
  for (int n = 0; n < N_; ++n) s += eb[n * E_ + t];
  ge[t] = s * (1.0f / 128.0f);
  fi[t] = eb[t];
  __syncthreads();
  float acc = bfix[t] + bstep[t];
#pragma unroll 4
  for (int g = 0; g < E_; ++g)
    acc += ge[g] * Wfix[g * E_ + t] + fi[g] * Wstep[g * E_ + t];
  qbase[b * E_ + t] = acc;
}

// ---------------------------------------------------------------- K3: c[b,n]
__global__ void k_c(const float* __restrict__ emb, const float* __restrict__ wc2,
                    const float* __restrict__ cconst, float* __restrict__ cvec) {
  __shared__ float w[E_];
  int t = threadIdx.x;
  w[t] = wc2[t];
  __syncthreads();
  int row = blockIdx.x * 256 + t;
  const float4* e4 = (const float4*)(emb + (size_t)row * E_);
  const float4* w4 = (const float4*)w;
  float acc = 0.f;
#pragma unroll 8
  for (int j = 0; j < E_ / 4; ++j) {
    float4 a = e4[j], bv = w4[j];
    acc += a.x * bv.x + a.y * bv.y + a.z * bv.z + a.w * bv.w;
  }
  cvec[row] = acc + *cconst;
}

// ---------------------------------------------------------------- K4: 16-wave rollout
// One block (1024 thr, 16 waves) per batch element. Wave w = 2h+u: head h,
// n-half u (n = u*64 + lane). Per-thread state = 96 floats (fits 128 VGPR,
// which the 1024-thread workgroup forces anyway -> no spill, 4 waves/SIMD).
// Split softmax: per-wave (m_u, S_u); alpha_u = exp(m_u - m) applied at the
// z phase via linearity. Two barriers/step. LSE on wave 0 only.
__global__ __launch_bounds__(1024)
void k_roll(const float* __restrict__ emb, const float* __restrict__ Wstep,
            const float* __restrict__ kT, const float* __restrict__ vv_,
            const float* __restrict__ lkT,
            const float* __restrict__ qbase, const float* __restrict__ cvec,
            float* __restrict__ out) {
  int lt = threadIdx.x;
  int b = blockIdx.x;
  int w = lt >> 6;      // wave id
  int j = lt & 63;      // lane
  int h = w >> 1;       // head
  int u = w & 1;        // n-half

  __shared__ float sq_lds[128 * 260];   // 130 KiB (stride 260: init-store bank spread)
  __shared__ float work[6144];          // 24 KiB overlay: init At/Bs | main-loop buffers
  float* at_s = work;                   // [16 waves][64]  wave-PRIVATE exp values
  float* mS_s = work + 1024;            // [16 waves][2]   (m_u, S_u)
  float* cxp2 = work + 1056;            // [16 waves][32]  ctx partials per (h,u)
  float* zp_s = work + 1568;            // [8 heads][128]  z partials

  // ---- init: sq_lds[n][e] = qbase[b][e] + sum_g emb[b][n][g] * Wstep[256+g][e]
  {
    float* At = work;           // [16][128]
    float* Bs = work + 2048;    // [16][256]
    const float4* eb4 = (const float4*)(emb + (size_t)b * 32768);
    const float* W2 = Wstep + 65536;
    int n0 = (lt & 31) * 4;
    int e0 = (lt >> 5) * 8;     // 32 e-groups of 8 (1024 threads)
    float acc[4][8];
#pragma unroll
    for (int i = 0; i < 4; ++i)
#pragma unroll
      for (int jj = 0; jj < 8; ++jj) acc[i][jj] = 0.f;

    for (int gc = 0; gc < 16; ++gc) {
      if (lt < 512) {
        int n = lt & 127, q4g = lt >> 7;
        float4 a = eb4[n * 64 + gc * 4 + q4g];
        At[(q4g * 4 + 0) * 128 + n] = a.x;
        At[(q4g * 4 + 1) * 128 + n] = a.y;
        At[(q4g * 4 + 2) * 128 + n] = a.z;
        At[(q4g * 4 + 3) * 128 + n] = a.w;
      }
      {
        const float4* w4 = (const float4*)(W2 + gc * 16 * 256);
        ((float4*)Bs)[lt] = w4[lt];   // 4096 floats = 1024 float4
      }
      __syncthreads();
#pragma unroll
      for (int gi = 0; gi < 16; ++gi) {
        float4 a4 = *(const float4*)(At + gi * 128 + n0);
        const float4* bp = (const float4*)(Bs + gi * 256 + e0);
        float4 b0 = bp[0], b1 = bp[1];
        float av[4] = {a4.x, a4.y, a4.z, a4.w};
        float bv[8] = {b0.x, b0.y, b0.z, b0.w, b1.x, b1.y, b1.z, b1.w};
#pragma unroll
        for (int i = 0; i < 4; ++i)
#pragma unroll
          for (int jj = 0; jj < 8; ++jj) acc[i][jj] += av[i] * bv[jj];
      }
      __syncthreads();
    }
    const float* qb = qbase + (size_t)b * 256;
    float qbr[8];
#pragma unroll
    for (int jj = 0; jj < 8; ++jj) qbr[jj] = qb[e0 + jj];
#pragma unroll
    for (int i = 0; i < 4; ++i)
#pragma unroll
      for (int jj = 0; jj < 8; ++jj)
        sq_lds[(n0 + i) * 260 + e0 + jj] = acc[i][jj] + qbr[jj];
  }
  __syncthreads();
  __builtin_amdgcn_sched_barrier(0);   // keep init acc[] live range from overlapping fills

  // ---- register fills: 96 floats/thread (coalesced) ----
  const float* kTb = kT + (size_t)b * 32768;
  const float* vb  = vv_ + (size_t)b * 32768;
  const float* lTb = lkT + (size_t)b * 32768;
  int nob = u * 64;                      // own n = nob + j

  float kr[32];                          // k[h][d][own n]
#pragma unroll
  for (int d = 0; d < 32; ++d) kr[d] = kTb[(h * 32 + d) * 128 + nob + j];

  int e_own = h * 32 + (j & 31);
  int nb = u * 2 + (j >> 5);             // 32-row n-block within head
  float vr[32];                          // v[nb*32+m][e_own]
#pragma unroll
  for (int m = 0; m < 32; ++m) vr[m] = vb[(nb * 32 + m) * 256 + e_own];

  float lr[32];                          // lk2[h-slice e][own n]
#pragma unroll
  for (int e = 0; e < 32; ++e) lr[e] = lTb[(h * 32 + e) * 128 + nob + j];

  float cv_lo = cvec[b * 128 + j];
  float cv_hi = cvec[b * 128 + 64 + j];
  int vis_lo = (j == 0) ? 1 : 0, vis_hi = 0;
  int cur = 0;
  float lp = 0.f;

#pragma unroll 1
  for (int it = 0; it < N_ - 1; ++it) {
    // --- A: own-half scores + per-wave softmax stats (no barrier) ---
    const float4* q4 = (const float4*)(sq_lds + cur * 260 + h * 32);
    float sa = 0.f, sb = 0.f;
#pragma unroll
    for (int dd = 0; dd < 8; ++dd) {
      float4 qv = q4[dd];
      float t = qv.x * kr[dd * 4] + qv.y * kr[dd * 4 + 1] +
                qv.z * kr[dd * 4 + 2] + qv.w * kr[dd * 4 + 3];
      if (dd & 1) sb += t; else sa += t;
    }
    int vis_own = u ? vis_hi : vis_lo;
    float sv = vis_own ? NEG : (sa + sb) * SCALE;
    float mw = wred_max(sv);
    float ev = expf(sv - mw);            // all-masked wave: exp(0)=1, killed by a_u=0
    float Sw = wred_sum(ev);
    at_s[w * 64 + j] = ev;               // wave-private; DS pipe is in-order per wave
    if (j == 0) { mS_s[w * 2] = mw; mS_s[w * 2 + 1] = Sw; }

    // --- B: raw ctx partial over own half (wave-local at_s read) ---
    const float4* a4 = (const float4*)(at_s + w * 64 + (j >> 5) * 32);
    float p0 = 0.f, p1 = 0.f;
#pragma unroll
    for (int mm = 0; mm < 8; ++mm) {
      float4 av = a4[mm];
      float t = av.x * vr[mm * 4] + av.y * vr[mm * 4 + 1] +
                av.z * vr[mm * 4 + 2] + av.w * vr[mm * 4 + 3];
      if (mm & 1) p1 += t; else p0 += t;
    }
    float p = p0 + p1;
    float ph = p + __shfl_xor(p, 32);    // combine the wave's two 32-n blocks
    if (j < 32) cxp2[w * 32 + j] = ph;
    __syncthreads();                     // barrier 1

    // --- Z: softmax-combine (alpha correction) + z partial for own n ---
    float m0 = mS_s[4 * h], S0 = mS_s[4 * h + 1];
    float m1 = mS_s[4 * h + 2], S1 = mS_s[4 * h + 3];
    float mh = fmaxf(m0, m1);
    float a0 = expf(m0 - mh), a1 = expf(m1 - mh);
    float inv = 1.0f / (S0 * a0 + S1 * a1);
    const float4* c0 = (const float4*)(cxp2 + (2 * h) * 32);
    const float4* c1 = (const float4*)(cxp2 + (2 * h + 1) * 32);
    float za0 = 0.f, za1 = 0.f, zb0 = 0.f, zb1 = 0.f;
#pragma unroll
    for (int ee = 0; ee < 8; ++ee) {
      float4 cv0 = c0[ee], cv1 = c1[ee];
      float t0 = cv0.x * lr[ee * 4] + cv0.y * lr[ee * 4 + 1] +
                 cv0.z * lr[ee * 4 + 2] + cv0.w * lr[ee * 4 + 3];
      float t1 = cv1.x * lr[ee * 4] + cv1.y * lr[ee * 4 + 1] +
                 cv1.z * lr[ee * 4 + 2] + cv1.w * lr[ee * 4 + 3];
      if (ee & 1) { za1 += t0; zb1 += t1; } else { za0 += t0; zb0 += t1; }
    }
    float z = (a0 * (za0 + za1) + a1 * (zb0 + zb1)) * inv;
    zp_s[h * 128 + nob + j] = z;
    __syncthreads();                     // barrier 2

    // --- C: redundant z assembly + argmax (all waves); LSE on wave 0 only ---
    float zlo = cv_lo, zhi = cv_hi;
#pragma unroll
    for (int hh = 0; hh < 8; ++hh) {
      zlo += zp_s[hh * 128 + j];
      zhi += zp_s[hh * 128 + 64 + j];
    }
    float zmlo = vis_lo ? -1e30f : zlo;
    float zmhi = vis_hi ? -1e30f : zhi;
    float vmax = wred_max(fmaxf(zmlo, zmhi));
    unsigned long long blo = __ballot(zmlo == vmax);
    int action;
    if (blo) action = __ffsll((unsigned long long)blo) - 1;
    else     action = 63 + __ffsll((unsigned long long)__ballot(zmhi == vmax));
    if (w == 0) {
      float lmax = CLIPV * tanhf(vmax * SCALE);
      float tlo = vis_lo ? 0.f : expf(CLIPV * tanhf(zlo * SCALE) - 10.0f);
      float thi = vis_hi ? 0.f : expf(CLIPV * tanhf(zhi * SCALE) - 10.0f);
      float S = wred_sum(tlo + thi);
      lp += lmax - 10.0f - logf(S);
    }
    cur = action;
    vis_lo |= (action == j);
    vis_hi |= (action == j + 64);
  }
  if (lt == 0) out[b] = lp;
}

// ---------------------------------------------------------------- launch
extern "C" void kernel_launch(void* const* d_in, const int* in_sizes, int n_in,
                              void* d_out, int out_size, void* d_ws, size_t ws_size,
                              hipStream_t stream) {
  (void)in_sizes; (void)n_in; (void)out_size; (void)ws_size;
  const float* emb   = (const float*)d_in[0];
  const float* Wqkv  = (const float*)d_in[1];
  const float* bqkv  = (const float*)d_in[2];
  const float* Wfix  = (const float*)d_in[3];
  const float* bfix  = (const float*)d_in[4];
  const float* Wstep = (const float*)d_in[5];
  const float* bstep = (const float*)d_in[6];
  const float* Wmlp  = (const float*)d_in[7];
  const float* bmlp  = (const float*)d_in[8];
  float* out = (float*)d_out;
  float* ws = (float*)d_ws;

  const size_t NBE = (size_t)B_ * N_ * E_;  // 16,777,216 floats
  float* kk_    = ws;                  // kT
  float* vv_    = ws + NBE;            // v
  float* lk2    = ws + 2 * NBE;        // lkT
  float* qbase  = ws + 3 * NBE;        // 131072
  float* cvec   = qbase + 131072;      // 65536
  float* Wc     = cvec + 65536;        // 65536
  float* bc     = Wc + 65536;          // 256
  float* wc2    = bc + 256;            // 256
  float* cconst = wc2 + 256;           // (64 pad)

  hipLaunchKernelGGL(k0_prep, dim3(257), dim3(256), 0, stream,
                     Wqkv, bqkv, Wmlp, bmlp, Wc, bc, wc2, cconst);
  hipLaunchKernelGGL(k_qbase, dim3(512), dim3(256), 0, stream,
                     emb, Wfix, bfix, Wstep, bstep, qbase);
  hipLaunchKernelGGL(k_c, dim3(256), dim3(256), 0, stream,
                     emb, wc2, cconst, cvec);
  hipLaunchKernelGGL(k_gemm, dim3(1024), dim3(256), 0, stream,
                     emb, Wqkv, bqkv, Wc, bc, kk_, vv_, lk2, 6, 0b101);
  hipLaunchKernelGGL(k_roll, dim3(512), dim3(1024), 0, stream,
                     emb, Wstep, kk_, vv_, lk2, qbase, cvec, out);
}

// Round 3
// 1271.737 us; speedup vs baseline: 1.2176x; 1.2176x over previous
//
#include <hip/hip_runtime.h>
#include <math.h>

// B=512, N=128, E=256, H=8, D=32. All fp32 (argmax fidelity requires it).
//
// Round-9: back to the R7 8-wave structure (best: 800us), with the remat-defeat.
//  Diagnosis across R5-R8: the per-thread k/v/lk arrays are pure loop-invariant
//  __restrict__ global loads -> the pre-RA scheduler REMATERIALIZES them inside
//  the 127-step loop to hit its default occupancy target (which ignores the LDS
//  cap of 1 block/CU). The arrays never reach RA as live ranges, so occupancy
//  attributes alone (R6: launch_bounds(512,1); R7: waves_per_eu(2,2); R8: 64-VGPR
//  16-wave split) never changed codegen. The ~100 floats/lane reloaded from L2
//  every step (~13GB/dispatch) IS the 800us.
//  Fix: (1) pin all 192 state floats with empty inline asm ("+v") after the
//  one-time fill - LLVM cannot remat inline asm, forcing true liveness;
//  (2) amdgpu_waves_per_eu(2,2) + flat_work_group_size(512,512) so RA gets the
//  256-VGPR/wave budget (512-reg SIMD file / 2 waves; 232-reg peak fits).
//  (3) R8's proven-safe trick: LSE (tanh/exp/log) on wave 0 only.

#define B_ 512
#define N_ 128
#define E_ 256
#define H_ 8
#define D_ 32
#define NEG (-1.0e9f)
#define CLIPV 10.0f
#define SCALE 0.17677669529663688110f  /* 1/sqrt(32), fp32-rounded */

// ---------------- wave-wide reductions (64 lanes) ----------------
template <int CTRL>
__device__ __forceinline__ float dpp_f(float x) {
  int r = __builtin_amdgcn_update_dpp(__float_as_int(x), __float_as_int(x),
                                      CTRL, 0xf, 0xf, false);
  return __int_as_float(r);
}
__device__ __forceinline__ float wred_max(float v) {
  v = fmaxf(v, dpp_f<0xB1>(v));    // quad_perm(1,0,3,2)  : xor 1
  v = fmaxf(v, dpp_f<0x4E>(v));    // quad_perm(2,3,0,1)  : xor 2
  v = fmaxf(v, dpp_f<0x124>(v));   // row_ror:4
  v = fmaxf(v, dpp_f<0x128>(v));   // row_ror:8
  v = fmaxf(v, __shfl_xor(v, 16));
  v = fmaxf(v, __shfl_xor(v, 32));
  return v;
}
__device__ __forceinline__ float wred_sum(float v) {
  v += dpp_f<0xB1>(v);
  v += dpp_f<0x4E>(v);
  v += dpp_f<0x124>(v);
  v += dpp_f<0x128>(v);
  v += __shfl_xor(v, 16);
  v += __shfl_xor(v, 32);
  return v;
}

// ---------------------------------------------------------------- K0: weight folds
__global__ void k0_prep(const float* __restrict__ Wqkv, const float* __restrict__ bqkv,
                        const float* __restrict__ Wmlp, const float* __restrict__ bmlp,
                        float* __restrict__ Wc, float* __restrict__ bc,
                        float* __restrict__ wc2, float* __restrict__ cconst) {
  int t = threadIdx.x;
  int blk = blockIdx.x;
  __shared__ float row_s[E_];
  if (blk < E_) {
    int g = blk;
    row_s[t] = Wqkv[g * 768 + 512 + t];
    __syncthreads();
    int f = t;
    const float4* wm4 = (const float4*)(Wmlp + f * E_);
    const float4* w34 = (const float4*)row_s;
    float acc = 0.f;
#pragma unroll 8
    for (int j = 0; j < E_ / 4; ++j) {
      float4 a = w34[j]; float4 bv = wm4[j];
      acc += a.x * bv.x + a.y * bv.y + a.z * bv.z + a.w * bv.w;
    }
    Wc[g * E_ + f] = acc;
  } else {
    int f = t;
    float a1 = 0.f, a2 = 0.f;
    for (int e = 0; e < E_; ++e) {
      a1 += bqkv[512 + e] * Wmlp[f * E_ + e];
      a2 += Wqkv[f * 768 + 512 + e] * bmlp[e];
    }
    bc[f] = a1;
    wc2[f] = a2;
    if (t == 0) {
      float c = 0.f;
      for (int e = 0; e < E_; ++e) c += bqkv[512 + e] * bmlp[e];
      *cconst = c;
    }
  }
}

// ---------------------------------------------------------------- K1: precompute GEMM (3 tensors)
__global__ __launch_bounds__(256, 2)
void k_gemm(const float* __restrict__ emb, const float* __restrict__ Wqkv,
            const float* __restrict__ bqkv,
            const float* __restrict__ Wc, const float* __restrict__ bc,
            float* __restrict__ kk_, float* __restrict__ vv_,
            float* __restrict__ lk2, int ncc, int tmask) {
  __shared__ float As[256 * 64];  // [kk][m], exactly 64 KiB
  int t = threadIdx.x;
  int r0 = blockIdx.x * 64;
  {
    int m = t >> 2;
    int c0 = t & 3;
    const float4* e4 = (const float4*)emb;
#pragma unroll
    for (int p = 0; p < 16; ++p) {
      int c4 = c0 + p * 4;
      float4 a = e4[(size_t)(r0 + m) * 64 + c4];
      As[(c4 * 4 + 0) * 64 + m] = a.x;
      As[(c4 * 4 + 1) * 64 + m] = a.y;
      As[(c4 * 4 + 2) * 64 + m] = a.z;
      As[(c4 * 4 + 3) * 64 + m] = a.w;
    }
  }
  __syncthreads();
  int tx = t & 15, ty = t >> 4;
  const float4* As4 = (const float4*)As;
  for (int cc = 0; cc < ncc; ++cc) {
    const float* Bp; int ldb4; const float* bias; float* outp;
    int colbase = (cc & 1) * 128;
    switch (cc >> 1) {
      case 0:  Bp = Wqkv + colbase;          ldb4 = 192; bias = bqkv + colbase;       outp = kk_; break;
      case 1:  Bp = Wqkv + 256 + colbase;    ldb4 = 192; bias = bqkv + 256 + colbase; outp = vv_; break;
      default: Bp = Wc + colbase;            ldb4 = 64;  bias = bc + colbase;         outp = lk2; break;
    }
    const float4* B4 = (const float4*)Bp;
    float acc[4][8];
#pragma unroll
    for (int i = 0; i < 4; ++i)
#pragma unroll
      for (int j = 0; j < 8; ++j) acc[i][j] = 0.f;

#pragma unroll 4
    for (int kk = 0; kk < 256; ++kk) {
      float4 b0 = B4[kk * ldb4 + tx * 2];
      float4 b1 = B4[kk * ldb4 + tx * 2 + 1];
      float4 av = As4[kk * 16 + ty];
      float a_[4] = {av.x, av.y, av.z, av.w};
#pragma unroll
      for (int i = 0; i < 4; ++i) {
        acc[i][0] += a_[i] * b0.x; acc[i][1] += a_[i] * b0.y;
        acc[i][2] += a_[i] * b0.z; acc[i][3] += a_[i] * b0.w;
        acc[i][4] += a_[i] * b1.x; acc[i][5] += a_[i] * b1.y;
        acc[i][6] += a_[i] * b1.z; acc[i][7] += a_[i] * b1.w;
      }
    }
    float bj[8];
#pragma unroll
    for (int j = 0; j < 8; ++j) bj[j] = bias ? bias[tx * 8 + j] : 0.f;
    int tr = (tmask >> (cc >> 1)) & 1;
    if (!tr) {
#pragma unroll
      for (int i = 0; i < 4; ++i) {
        int row = r0 + ty * 4 + i;
        float4 o0 = make_float4(acc[i][0] + bj[0], acc[i][1] + bj[1], acc[i][2] + bj[2], acc[i][3] + bj[3]);
        float4 o1 = make_float4(acc[i][4] + bj[4], acc[i][5] + bj[5], acc[i][6] + bj[6], acc[i][7] + bj[7]);
        float4* o4 = (float4*)(outp + (size_t)row * 256 + colbase + tx * 8);
        o4[0] = o0; o4[1] = o1;
      }
    } else {
#pragma unroll
      for (int i = 0; i < 4; ++i) {
        int row = r0 + ty * 4 + i;
        int bb = row >> 7, nn = row & 127;
        float* op = outp + (size_t)bb * 32768 + nn;
#pragma unroll
        for (int j = 0; j < 8; ++j)
          op[(size_t)(colbase + tx * 8 + j) * 128] = acc[i][j] + bj[j];
      }
    }
  }
}

// ---------------------------------------------------------------- K2: qbase per b
__global__ void k_qbase(const float* __restrict__ emb, const float* __restrict__ Wfix,
                        const float* __restrict__ bfix, const float* __restrict__ Wstep,
                        const float* __restrict__ bstep, float* __restrict__ qbase) {
  int b = blockIdx.x, t = threadIdx.x;
  __shared__ float ge[E_], fi[E_];
  const float* eb = emb + (size_t)b * N_ * E_;
  float s = 0.f;
#pragma unroll 8
  for (int n = 0; n < N_; ++n) s += eb[n * E_ + t];
  ge[t] = s * (1.0f / 128.0f);
  fi[t] = eb[t];
  __syncthreads();
  float acc = bfix[t] + bstep[t];
#pragma unroll 4
  for (int g = 0; g < E_; ++g)
    acc += ge[g] * Wfix[g * E_ + t] + fi[g] * Wstep[g * E_ + t];
  qbase[b * E_ + t] = acc;
}

// ---------------------------------------------------------------- K3: c[b,n]
__global__ void k_c(const float* __restrict__ emb, const float* __restrict__ wc2,
                    const float* __restrict__ cconst, float* __restrict__ cvec) {
  __shared__ float w[E_];
  int t = threadIdx.x;
  w[t] = wc2[t];
  __syncthreads();
  int row = blockIdx.x * 256 + t;
  const float4* e4 = (const float4*)(emb + (size_t)row * E_);
  const float4* w4 = (const float4*)w;
  float acc = 0.f;
#pragma unroll 8
  for (int j = 0; j < E_ / 4; ++j) {
    float4 a = e4[j], bv = w4[j];
    acc += a.x * bv.x + a.y * bv.y + a.z * bv.z + a.w * bv.w;
  }
  cvec[row] = acc + *cconst;
}

// ---------------------------------------------------------------- K4: wave-per-head rollout
// One block (512 thr, 8 waves) per batch element. Wave h == head h.
// waves_per_eu(2,2): LDS (154KB) caps us at 1 block/CU = 2 waves/SIMD anyway,
// so grant RA the full 256-VGPR/wave budget. The asm pins below are what force
// the 192 state floats to be LIVE (remat-proof) so that budget is actually used.
__global__ __attribute__((amdgpu_flat_work_group_size(512, 512), amdgpu_waves_per_eu(2, 2)))
void k_roll(const float* __restrict__ emb, const float* __restrict__ Wstep,
            const float* __restrict__ kT, const float* __restrict__ vv_,
            const float* __restrict__ lkT,
            const float* __restrict__ qbase, const float* __restrict__ cvec,
            float* __restrict__ out) {
  int lt = threadIdx.x;
  int b = blockIdx.x;
  int h = lt >> 6;      // wave = head
  int j = lt & 63;      // lane

  __shared__ float sq_lds[128 * 260];   // 130 KiB (stride 260: init-store bank spread)
  __shared__ float work[6144];          // 24 KiB overlay: init At/Bs | at_s/ctx_s/zp
  float* at_s  = work;                  // [8][128] wave-private slices
  float* ctx_s = work + 1024;           // [8][32]  wave-private slices
  float* zp    = work + 1280;           // [2][8][128] double-buffered

  // ---- init: sq_lds[n][e] = qbase[b][e] + sum_g emb[b][n][g] * Wstep[256+g][e]
  {
    float* At = work;           // [16][128]
    float* Bs = work + 2048;    // [16][256]
    const float4* eb4 = (const float4*)(emb + (size_t)b * 32768);
    const float* W2 = Wstep + 65536;
    int n0 = (lt & 31) * 4;
    int e0 = (lt >> 5) * 16;
    float acc[4][16];
#pragma unroll
    for (int i = 0; i < 4; ++i)
#pragma unroll
      for (int jj = 0; jj < 16; ++jj) acc[i][jj] = 0.f;

    for (int gc = 0; gc < 16; ++gc) {
      {
        int n = lt & 127, q4g = lt >> 7;
        float4 a = eb4[n * 64 + gc * 4 + q4g];
        At[(q4g * 4 + 0) * 128 + n] = a.x;
        At[(q4g * 4 + 1) * 128 + n] = a.y;
        At[(q4g * 4 + 2) * 128 + n] = a.z;
        At[(q4g * 4 + 3) * 128 + n] = a.w;
      }
      {
        const float4* w4 = (const float4*)(W2 + gc * 16 * 256);
        ((float4*)Bs)[lt] = w4[lt];
        ((float4*)Bs)[lt + 512] = w4[lt + 512];
      }
      __syncthreads();
#pragma unroll
      for (int gi = 0; gi < 16; ++gi) {
        float4 a4 = *(const float4*)(At + gi * 128 + n0);
        const float4* bp = (const float4*)(Bs + gi * 256 + e0);
        float4 b0 = bp[0], b1 = bp[1], b2 = bp[2], b3 = bp[3];
        float av[4] = {a4.x, a4.y, a4.z, a4.w};
        float bv[16] = {b0.x, b0.y, b0.z, b0.w, b1.x, b1.y, b1.z, b1.w,
                        b2.x, b2.y, b2.z, b2.w, b3.x, b3.y, b3.z, b3.w};
#pragma unroll
        for (int i = 0; i < 4; ++i)
#pragma unroll
          for (int jj = 0; jj < 16; ++jj) acc[i][jj] += av[i] * bv[jj];
      }
      __syncthreads();
    }
    const float* qb = qbase + (size_t)b * 256;
    float qbr[16];
#pragma unroll
    for (int jj = 0; jj < 16; ++jj) qbr[jj] = qb[e0 + jj];
#pragma unroll
    for (int i = 0; i < 4; ++i)
#pragma unroll
      for (int jj = 0; jj < 16; ++jj)
        sq_lds[(n0 + i) * 260 + e0 + jj] = acc[i][jj] + qbr[jj];  // scalar: 2-way banks
  }
  __syncthreads();
  __builtin_amdgcn_sched_barrier(0);   // keep init acc[] live range from overlapping fills

  // ---- register fills (coalesced within 32/64-lane groups) ----
  // asm("" : "+v"(x)) after each fill: LLVM cannot rematerialize inline asm, so
  // these 192 floats become true live ranges instead of per-step L2 reloads.
  const float* kTb = kT + (size_t)b * 32768;
  const float* vb  = vv_ + (size_t)b * 32768;
  const float* lTb = lkT + (size_t)b * 32768;

  float k0r[32], k1r[32];     // k[h][d][j], k[h][d][j+64]
#pragma unroll
  for (int d = 0; d < 32; ++d) {
    k0r[d] = kTb[(h * 32 + d) * 128 + j];
    k1r[d] = kTb[(h * 32 + d) * 128 + j + 64];
    asm("" : "+v"(k0r[d]));
    asm("" : "+v"(k1r[d]));
  }
  int e_own = h * 32 + (j & 31), nh = j >> 5;
  float vr[64];               // v[nh*64+m][e_own]
#pragma unroll
  for (int m = 0; m < 64; ++m) {
    vr[m] = vb[(nh * 64 + m) * 256 + e_own];
    asm("" : "+v"(vr[m]));
  }
  float l0r[32], l1r[32];     // lk2[j][h-slice], lk2[j+64][h-slice]
#pragma unroll
  for (int e = 0; e < 32; ++e) {
    l0r[e] = lTb[(h * 32 + e) * 128 + j];
    l1r[e] = lTb[(h * 32 + e) * 128 + j + 64];
    asm("" : "+v"(l0r[e]));
    asm("" : "+v"(l1r[e]));
  }
  float cv_lo = cvec[b * 128 + j];
  float cv_hi = cvec[b * 128 + j + 64];
  int vis_lo = (j == 0) ? 1 : 0, vis_hi = 0;
  int cur = 0;
  float lp = 0.f;

#pragma unroll 1
  for (int it = 0; it < N_ - 1; ++it) {
    // --- scores (wave-local; q row broadcast-read from sq_lds) ---
    const float4* q4 = (const float4*)(sq_lds + cur * 260 + h * 32);
    float sa0 = 0.f, sb0 = 0.f, sa1 = 0.f, sb1 = 0.f;
#pragma unroll
    for (int dd = 0; dd < 8; ++dd) {
      float4 qv = q4[dd];
      if (dd & 1) {
        sb0 += qv.x * k0r[dd * 4] + qv.y * k0r[dd * 4 + 1] + qv.z * k0r[dd * 4 + 2] + qv.w * k0r[dd * 4 + 3];
        sb1 += qv.x * k1r[dd * 4] + qv.y * k1r[dd * 4 + 1] + qv.z * k1r[dd * 4 + 2] + qv.w * k1r[dd * 4 + 3];
      } else {
        sa0 += qv.x * k0r[dd * 4] + qv.y * k0r[dd * 4 + 1] + qv.z * k0r[dd * 4 + 2] + qv.w * k0r[dd * 4 + 3];
        sa1 += qv.x * k1r[dd * 4] + qv.y * k1r[dd * 4 + 1] + qv.z * k1r[dd * 4 + 2] + qv.w * k1r[dd * 4 + 3];
      }
    }
    float slo = vis_lo ? NEG : (sa0 + sb0) * SCALE;
    float shi = vis_hi ? NEG : (sa1 + sb1) * SCALE;
    // --- softmax (in-wave; division deferred) ---
    float m = wred_max(fmaxf(slo, shi));
    float elo = expf(slo - m), ehi = expf(shi - m);
    at_s[h * 128 + j] = elo;
    at_s[h * 128 + 64 + j] = ehi;
    float inv = 1.0f / wred_sum(elo + ehi);
    // --- ctx for e_own over n-half (wave-local LDS read, no barrier) ---
    const float4* a4 = (const float4*)(at_s + h * 128 + nh * 64);
    float c0 = 0.f, c1 = 0.f;
#pragma unroll
    for (int mm = 0; mm < 16; ++mm) {
      float4 av = a4[mm];
      if (mm & 1)
        c1 += av.x * vr[mm * 4] + av.y * vr[mm * 4 + 1] + av.z * vr[mm * 4 + 2] + av.w * vr[mm * 4 + 3];
      else
        c0 += av.x * vr[mm * 4] + av.y * vr[mm * 4 + 1] + av.z * vr[mm * 4 + 2] + av.w * vr[mm * 4 + 3];
    }
    float c = c0 + c1;
    c += __shfl_xor(c, 32);     // combine n-halves (lanes j, j^32 share e_own)
    c *= inv;
    if (j < 32) ctx_s[h * 32 + j] = c;
    // --- z partial for head-slice (wave-local broadcast read) ---
    const float4* cx4 = (const float4*)(ctx_s + h * 32);
    float z0a = 0.f, z0b = 0.f, z1a = 0.f, z1b = 0.f;
#pragma unroll
    for (int ee = 0; ee < 8; ++ee) {
      float4 cv = cx4[ee];
      if (ee & 1) {
        z0b += cv.x * l0r[ee * 4] + cv.y * l0r[ee * 4 + 1] + cv.z * l0r[ee * 4 + 2] + cv.w * l0r[ee * 4 + 3];
        z1b += cv.x * l1r[ee * 4] + cv.y * l1r[ee * 4 + 1] + cv.z * l1r[ee * 4 + 2] + cv.w * l1r[ee * 4 + 3];
      } else {
        z0a += cv.x * l0r[ee * 4] + cv.y * l0r[ee * 4 + 1] + cv.z * l0r[ee * 4 + 2] + cv.w * l0r[ee * 4 + 3];
        z1a += cv.x * l1r[ee * 4] + cv.y * l1r[ee * 4 + 1] + cv.z * l1r[ee * 4 + 2] + cv.w * l1r[ee * 4 + 3];
      }
    }
    float* zpw = zp + (it & 1) * 1024;
    zpw[h * 128 + j] = z0a + z0b;
    zpw[h * 128 + 64 + j] = z1a + z1b;
    __syncthreads();   // the ONLY barrier per step

    // --- phase C: every wave redundantly assembles z + argmax; LSE wave 0 only ---
    float zlo = cv_lo, zhi = cv_hi;
#pragma unroll
    for (int hh = 0; hh < 8; ++hh) {
      zlo += zpw[hh * 128 + j];
      zhi += zpw[hh * 128 + 64 + j];
    }
    float zmlo = vis_lo ? -1e30f : zlo;
    float zmhi = vis_hi ? -1e30f : zhi;
    float vmax = wred_max(fmaxf(zmlo, zmhi));
    unsigned long long blo = __ballot(zmlo == vmax);
    int action;
    if (blo) action = __ffsll((unsigned long long)blo) - 1;
    else     action = 63 + __ffsll((unsigned long long)__ballot(zmhi == vmax));
    if (h == 0) {
      float lmax = CLIPV * tanhf(vmax * SCALE);
      float tlo = vis_lo ? 0.f : expf(CLIPV * tanhf(zlo * SCALE) - 10.0f);
      float thi = vis_hi ? 0.f : expf(CLIPV * tanhf(zhi * SCALE) - 10.0f);
      float S = wred_sum(tlo + thi);
      lp += lmax - 10.0f - logf(S);
    }
    cur = action;
    vis_lo |= (action == j);
    vis_hi |= (action == j + 64);
  }
  if (lt == 0) out[b] = lp;
}

// ---------------------------------------------------------------- launch
extern "C" void kernel_launch(void* const* d_in, const int* in_sizes, int n_in,
                              void* d_out, int out_size, void* d_ws, size_t ws_size,
                              hipStream_t stream) {
  (void)in_sizes; (void)n_in; (void)out_size; (void)ws_size;
  const float* emb   = (const float*)d_in[0];
  const float* Wqkv  = (const float*)d_in[1];
  const float* bqkv  = (const float*)d_in[2];
  const float* Wfix  = (const float*)d_in[3];
  const float* bfix  = (const float*)d_in[4];
  const float* Wstep = (const float*)d_in[5];
  const float* bstep = (const float*)d_in[6];
  const float* Wmlp  = (const float*)d_in[7];
  const float* bmlp  = (const float*)d_in[8];
  float* out = (float*)d_out;
  float* ws = (float*)d_ws;

  const size_t NBE = (size_t)B_ * N_ * E_;  // 16,777,216 floats
  float* kk_    = ws;                  // kT
  float* vv_    = ws + NBE;            // v
  float* lk2    = ws + 2 * NBE;        // lkT
  float* qbase  = ws + 3 * NBE;        // 131072
  float* cvec   = qbase + 131072;      // 65536
  float* Wc     = cvec + 65536;        // 65536
  float* bc     = Wc + 65536;          // 256
  float* wc2    = bc + 256;            // 256
  float* cconst = wc2 + 256;           // (64 pad)

  hipLaunchKernelGGL(k0_prep, dim3(257), dim3(256), 0, stream,
                     Wqkv, bqkv, Wmlp, bmlp, Wc, bc, wc2, cconst);
  hipLaunchKernelGGL(k_qbase, dim3(512), dim3(256), 0, stream,
                     emb, Wfix, bfix, Wstep, bstep, qbase);
  hipLaunchKernelGGL(k_c, dim3(256), dim3(256), 0, stream,
                     emb, wc2, cconst, cvec);
  hipLaunchKernelGGL(k_gemm, dim3(1024), dim3(256), 0, stream,
                     emb, Wqkv, bqkv, Wc, bc, kk_, vv_, lk2, 6, 0b101);
  hipLaunchKernelGGL(k_roll, dim3(512), dim3(512), 0, stream,
                     emb, Wstep, kk_, vv_, lk2, qbase, cvec, out);
}